// Round 7
// baseline (305.435 us; speedup 1.0000x reference)
//
#include <hip/hip_runtime.h>
#include <hip/hip_bf16.h>

// Problem: B=4,S=4096 tokens (16384), HIDDEN=1024, 16 heads x 64 dim.
// "Attention" mixes HEADS per token (16x16 softmax over heads), not sequence.
// Inputs/output fp32; compute bf16-MFMA w/ fp32 accumulate.
//
// R11 -> R12 (R11: 292.3us, attn re-pipelining NULL => attn is likely small
// (~10us by latency ledger) and ~100us is unaccounted (Wo/cvt/unknown,
// invisible below the 114us top-5 cutoff). QKV=115us/880TF/Occ 21% = 1
// block/CU (128KB LDS + 128 acc regs) is the PROVEN cost: every vmcnt wall
// + barrier fully exposed, no co-resident block (m97's overlap mechanism)):
//  GEMM: 256x128 tile, BK=32, 8 waves of 64x64 (acc[4][4]=64 regs), dbuf
//  48KB LDS, __launch_bounds__(512,4) -> 2 blocks/CU. R5's proven
//  zero-conflict BK=32 swizzle pair. Per K-tile: {stage(t+1) 3 loads;
//  VMCNT(3) [ledger-exact: leaves loads(t+1)]; BAR; 8 b128 frag reads;
//  16 MFMA; BAR}. WAR: frag reads of a buffer complete (lgkm before MFMA)
//  before its end-barrier; overwrite issues >=1 barrier later.
//  Wo grid 512 blocks -> 2/CU overlapped (helps if Wo is the hidden cost);
//  QKV grid 1536. Also lowers QKV under the mystery dispatch so it surfaces
//  in next round's top-5.
//  ATTN/cvt: byte-identical to R11 (one variable per round).

typedef __bf16 bf16;
typedef __attribute__((ext_vector_type(8))) __bf16 bf16x8;
typedef __attribute__((ext_vector_type(4))) float floatx4;

#define HIDDEN 1024
#define BM 128
#define BN 128
#define BK 32

#define FENCE() asm volatile("" ::: "memory")
#define BAR()                                                                  \
    do {                                                                       \
        FENCE();                                                               \
        __builtin_amdgcn_s_barrier();                                          \
        FENCE();                                                               \
    } while (0)
#define VMCNT(N) asm volatile("s_waitcnt vmcnt(" #N ")" ::: "memory")

__device__ __forceinline__ void async_load16(const bf16* g, bf16* lds) {
    __builtin_amdgcn_global_load_lds(
        (const __attribute__((address_space(1))) void*)g,
        (__attribute__((address_space(3))) void*)lds, 16, 0, 0);
}

__device__ __forceinline__ bf16x8 load8(const bf16* p) {
    return *(const bf16x8*)p;
}
__device__ __forceinline__ bf16x8 load8(const float* p) {
    floatx4 lo = *(const floatx4*)p;
    floatx4 hi = *(const floatx4*)(p + 4);
    bf16x8 r;
#pragma unroll
    for (int i = 0; i < 4; ++i) { r[i] = (bf16)lo[i]; r[i + 4] = (bf16)hi[i]; }
    return r;
}

// ---------- one-time fp32 -> bf16 conversion: x then packed wq|wk|wv|wo ----
__global__ __launch_bounds__(256) void cvt_all(
    const float* __restrict__ x,
    const float* __restrict__ wq, const float* __restrict__ wk,
    const float* __restrict__ wv, const float* __restrict__ wo,
    bf16* __restrict__ xb, bf16* __restrict__ wpk, int mh8)
{
    const int per = (HIDDEN * HIDDEN) / 8;   // 131072 chunks per weight
    int i = blockIdx.x * 256 + threadIdx.x;
    if (i < mh8) {
        *(bf16x8*)&xb[(size_t)i * 8] = load8(&x[(size_t)i * 8]);
    } else {
        int j = i - mh8;
        int wsel = j / per;
        int off  = (j - wsel * per) * 8;
        const float* s = wsel == 0 ? wq : wsel == 1 ? wk : wsel == 2 ? wv : wo;
        *(bf16x8*)&wpk[(size_t)j * 8] = load8(&s[off]);
    }
}

// ---------- 256x128-tile dbuf GEMM, 2 blocks/CU --------------------------
// C[m,n] = sum_k A[m,k]*W[n,k]. 512 thr = 8 waves (4M x 2N), wave tile
// 64x64, acc[4][4]. LDS 48KB: sA[2][256x32] + sB[2][128x32].
// Swizzle (R5-proven pair, 0 conflicts): stage kc=(c&3)^((row>>1)&3),
// read chunk = quad^((col>>1)&3). Bases are mult of 16 so the pair matches.

// stage one tile: NCH 16B-chunks per thread (A: NCH=2 -> 256 rows; B: 1).
template <int NCH>
__device__ __forceinline__ void stage_tile(const bf16* __restrict__ g, int ld,
                                           int kt, bf16* lds, int tid) {
#pragma unroll
    for (int j = 0; j < NCH; ++j) {
        const int c   = j * 512 + tid;
        const int row = c >> 2;
        const int kc  = (c & 3) ^ ((row >> 1) & 3);
        async_load16(&g[(size_t)row * ld + kt + kc * 8], &lds[c * 8]);
    }
}

__device__ __forceinline__ bf16x8 ldfrag(const bf16* buf, int base, int col,
                                         int quad) {
    return *(const bf16x8*)&buf[(base + col) * 32 +
                                (quad ^ ((col >> 1) & 3)) * 8];
}

template <typename TC>
__global__ __launch_bounds__(512, 4) void gemm_oc(
    const bf16* __restrict__ A, const bf16* __restrict__ W,
    TC* __restrict__ C, int K, int lda, int ldc)
{
    __shared__ __align__(16) bf16 sA[2][256 * 32];   // 32 KB
    __shared__ __align__(16) bf16 sB[2][128 * 32];   // 16 KB

    const int tid  = threadIdx.x;
    const int lane = tid & 63;
    const int w    = tid >> 6;       // 0..7
    const int wm   = w >> 1;         // 0..3 (m-64 group)
    const int wn   = w & 1;          // 0..1 (n-64 group)
    const int m0   = blockIdx.x * 256;
    const int n0   = blockIdx.y * 128;
    const int col  = lane & 15;
    const int quad = lane >> 4;

    const bf16* Ab = A + (size_t)m0 * lda;
    const bf16* Wb = W + (size_t)n0 * K;

    floatx4 acc[4][4] = {};

    const int T = K / 32;

    // Prologue: tile0 only (3 loads/thread).
    stage_tile<2>(Ab, lda, 0, sA[0], tid);
    stage_tile<1>(Wb, K,   0, sB[0], tid);

    for (int t = 0; t < T; ++t) {
        const bf16* cA = sA[t & 1];
        const bf16* cB = sB[t & 1];

        // Stage t+1; ledger: outstanding = loads(t)(3) + loads(t+1)(3);
        // VMCNT(3) -> loads(t) complete, loads(t+1) in flight.
        if (t + 1 < T) {
            stage_tile<2>(Ab, lda, (t + 1) * 32, sA[(t + 1) & 1], tid);
            stage_tile<1>(Wb, K,   (t + 1) * 32, sB[(t + 1) & 1], tid);
            VMCNT(3);
        } else {
            VMCNT(0);
        }
        BAR();

        bf16x8 a[4], b[4];
#pragma unroll
        for (int mi = 0; mi < 4; ++mi)
            a[mi] = ldfrag(cA, wm * 64 + mi * 16, col, quad);
#pragma unroll
        for (int ni = 0; ni < 4; ++ni)
            b[ni] = ldfrag(cB, wn * 64 + ni * 16, col, quad);

        __builtin_amdgcn_s_setprio(1);
#pragma unroll
        for (int mi = 0; mi < 4; ++mi)
#pragma unroll
            for (int ni = 0; ni < 4; ++ni)
                acc[mi][ni] = __builtin_amdgcn_mfma_f32_16x16x32_bf16(
                    a[mi], b[ni], acc[mi][ni], 0, 0, 0);
        __builtin_amdgcn_s_setprio(0);
        BAR();
    }

#pragma unroll
    for (int mi = 0; mi < 4; ++mi) {
#pragma unroll
        for (int r = 0; r < 4; ++r) {
            const int row = m0 + wm * 64 + mi * 16 + quad * 4 + r;
#pragma unroll
            for (int ni = 0; ni < 4; ++ni) {
                const int cc = n0 + wn * 64 + ni * 16 + col;
                C[(size_t)row * ldc + cc] = (TC)acc[mi][ni][r];
            }
        }
    }
}

// ---------- R3 fallback GEMM (fp32-or-bf16 in, register staging) ----------
template <typename TA, typename TB, typename TC>
__global__ __launch_bounds__(256, 2) void gemm_bt(
    const TA* __restrict__ A, const TB* __restrict__ W,
    TC* __restrict__ C, int M, int N, int K)
{
    __shared__ __align__(16) bf16 sA[BM * BK];
    __shared__ __align__(16) bf16 sB[BN * BK];

    const int tid  = threadIdx.x;
    const int lane = tid & 63;
    const int w    = tid >> 6;
    const int wm   = w >> 1;
    const int wn   = w & 1;
    const int m0   = blockIdx.x * BM;
    const int n0   = blockIdx.y * BN;
    const int col  = lane & 15;
    const int quad = lane >> 4;

    floatx4 acc[4][4] = {};

    for (int kt = 0; kt < K; kt += BK) {
        bf16x8 ga[2], gb[2];
#pragma unroll
        for (int i = 0; i < 2; ++i) {
            const int c   = i * 256 + tid;
            const int row = c >> 2;
            const int kc  = c & 3;
            ga[i] = load8(&A[(size_t)(m0 + row) * K + kt + kc * 8]);
            gb[i] = load8(&W[(size_t)(n0 + row) * K + kt + kc * 8]);
        }
        __syncthreads();
#pragma unroll
        for (int i = 0; i < 2; ++i) {
            const int c = i * 256 + tid;
            *(bf16x8*)&sA[c * 8] = ga[i];
            *(bf16x8*)&sB[c * 8] = gb[i];
        }
        __syncthreads();

        bf16x8 af[4], bfr[4];
#pragma unroll
        for (int mi = 0; mi < 4; ++mi)
            af[mi] = *(const bf16x8*)&sA[(wm * 64 + mi * 16 + col) * BK + quad * 8];
#pragma unroll
        for (int ni = 0; ni < 4; ++ni)
            bfr[ni] = *(const bf16x8*)&sB[(wn * 64 + ni * 16 + col) * BK + quad * 8];

#pragma unroll
        for (int mi = 0; mi < 4; ++mi)
#pragma unroll
            for (int ni = 0; ni < 4; ++ni)
                acc[mi][ni] = __builtin_amdgcn_mfma_f32_16x16x32_bf16(
                    af[mi], bfr[ni], acc[mi][ni], 0, 0, 0);
    }

#pragma unroll
    for (int mi = 0; mi < 4; ++mi) {
#pragma unroll
        for (int r = 0; r < 4; ++r) {
            const int row = m0 + wm * 64 + mi * 16 + quad * 4 + r;
#pragma unroll
            for (int ni = 0; ni < 4; ++ni) {
                const int cc = n0 + wn * 64 + ni * 16 + col;
                C[(size_t)row * N + cc] = (TC)acc[mi][ni][r];
            }
        }
    }
}

// ---------- per-token head-mixing attention, 4 tokens/wave (R11 exact) ---
__global__ __launch_bounds__(256) void attn_heads(
    bf16* base, size_t koff, size_t voff, int stride, bf16* ob)
{
    __shared__ __align__(16) bf16 sQ[4][2][3072];    // [wave][dbuf] q|k|v
    __shared__ __align__(16) bf16 sP[4][16 * 40];    // [wave] P, pad-40 rows
    __shared__ __align__(16) bf16 sO[4][1024];       // [wave] O-tile, 8B swz

    const int tid   = threadIdx.x;
    const int lane  = tid & 63;
    const int w     = tid >> 6;
    const int col   = lane & 15;
    const int quad  = lane >> 4;
    const int t0    = blockIdx.x * 16 + w * 4;       // wave's first token

    auto stage = [&](int tok, int s) {
        const bf16* qt = base + (size_t)tok * stride;
#pragma unroll
        for (int i = 0; i < 6; ++i) {
            const int ci = i * 64 + lane;            // linear 16B chunk
            const int rl = (ci >> 3) & 15;           // row within region
            const int cs = (ci & 7) ^ (rl & 7);
            const bf16* src = (i < 2) ? qt : (i < 4) ? qt + koff : qt + voff;
            async_load16(&src[(rl * 8 + cs) * 8], &sQ[w][s][ci * 8]);
        }
    };

    stage(t0, 0);

#pragma unroll
    for (int it = 0; it < 4; ++it) {
        if (it < 3) stage(t0 + it + 1, (it + 1) & 1);
        if (it == 0)      { VMCNT(6);  }
        else if (it < 3)  { VMCNT(10); }
        else              { VMCNT(4);  }

        const bf16* sq = sQ[w][it & 1];
        bf16* ot = ob + (size_t)(t0 + it) * HIDDEN;

        // S = Q K^T : conflict-free swizzled b128 frag reads.
        bf16x8 qa[2], kb[2];
#pragma unroll
        for (int kk = 0; kk < 2; ++kk) {
            const int c = ((kk << 2) + quad) ^ (col & 7);
            qa[kk] = *(const bf16x8*)&sq[(col * 8 + c) * 8];
            kb[kk] = *(const bf16x8*)&sq[((16 + col) * 8 + c) * 8];
        }
        floatx4 s = {};
        s = __builtin_amdgcn_mfma_f32_16x16x32_bf16(qa[0], kb[0], s, 0, 0, 0);
        s = __builtin_amdgcn_mfma_f32_16x16x32_bf16(qa[1], kb[1], s, 0, 0, 0);

        // PV A-frag: va[dt][j] = V[g=quad*8+j][d=dt*16+col]; quad>=2 zero.
        bf16x8 va[4] = {};
        if (quad < 2) {
#pragma unroll
            for (int dt = 0; dt < 4; ++dt) {
                const int cb = dt * 2 + (col >> 3);
#pragma unroll
                for (int j = 0; j < 8; ++j) {
                    const int r = 32 + quad * 8 + j;
                    va[dt][j] = sq[(r * 8 + (cb ^ j)) * 8 + (col & 7)];
                }
            }
        }

        // Max-free softmax over g (S/8 ~ N(0,1); fp32-safe).
#pragma unroll
        for (int r = 0; r < 4; ++r) {
            float e = __expf(s[r] * 0.125f);
            float su = e;
#pragma unroll
            for (int off = 1; off < 16; off <<= 1)
                su += __shfl_xor(su, off);
            sP[w][(quad * 4 + r) * 40 + col] = (bf16)(e / su);
        }

        // O = P V with swap: D -> O[h=col][d=dt*16+quad*4+r] (d-contig).
        bf16x8 pa = {};
        if (quad < 2) pa = *(const bf16x8*)&sP[w][col * 40 + quad * 8];
#pragma unroll
        for (int dt = 0; dt < 4; ++dt) {
            floatx4 o4 = {};
            o4 = __builtin_amdgcn_mfma_f32_16x16x32_bf16(va[dt], pa, o4, 0, 0, 0);
            union { bf16 h4[4]; uint2 u; } pk;
#pragma unroll
            for (int r = 0; r < 4; ++r) pk.h4[r] = (bf16)o4[r];
            const int c8 = dt * 4 + quad;
            *(uint2*)&sO[w][(col * 16 + (c8 ^ col)) * 4] = pk.u;
        }

        // Coalesced O out: 4 x (64 lanes x 8B) = 512B runs.
#pragma unroll
        for (int st = 0; st < 4; ++st) {
            const int n8 = st * 64 + lane;
            const int h = n8 >> 4, c8 = n8 & 15;
            const uint2 d = *(const uint2*)&sO[w][(h * 16 + (c8 ^ h)) * 4];
            *(uint2*)&ot[n8 * 4] = d;
        }
    }
}

extern "C" void kernel_launch(void* const* d_in, const int* in_sizes, int n_in,
                              void* d_out, int out_size, void* d_ws, size_t ws_size,
                              hipStream_t stream) {
    const float* x  = (const float*)d_in[0];
    const float* wq = (const float*)d_in[1];
    const float* wk = (const float*)d_in[2];
    const float* wv = (const float*)d_in[3];
    const float* wo = (const float*)d_in[4];
    float* out = (float*)d_out;

    const int M = in_sizes[0] / HIDDEN;   // 16384 tokens
    const size_t MH = (size_t)M * HIDDEN;
    const size_t WH = (size_t)HIDDEN * HIDDEN;

    const size_t need = (MH + 4 * WH + (size_t)M * 3 * HIDDEN) * sizeof(bf16);

    if (ws_size >= need && (M % 256) == 0) {
        // Fast path: convert once, 256x128-tile dbuf bf16 GEMMs.
        bf16* xb  = (bf16*)d_ws;          // [M][1024]; reused as O after QKV
        bf16* wpk = xb + MH;              // [4][1024][1024] packed q|k|v|o
        bf16* qkv = wpk + 4 * WH;         // [M][3072]

        const int mh8 = (int)(MH / 8);
        const int nchunks = mh8 + (int)(4 * WH / 8);
        cvt_all<<<dim3(nchunks / 256), 256, 0, stream>>>(x, wq, wk, wv, wo,
                                                         xb, wpk, mh8);

        gemm_oc<bf16><<<dim3(M / 256, 3 * HIDDEN / 128), 512, 0, stream>>>(
            xb, wpk, qkv, HIDDEN, HIDDEN, 3 * HIDDEN);

        // xb is dead now; attn writes O into it (dense lda=1024 for Wo GEMM).
        attn_heads<<<dim3(M / 16), 256, 0, stream>>>(qkv, 1024, 2048,
                                                     3 * HIDDEN, xb);

        gemm_oc<float><<<dim3(M / 256, HIDDEN / 128), 512, 0, stream>>>(
            xb, wpk + 3 * WH, out, HIDDEN, HIDDEN, HIDDEN);
    } else {
        // R3 proven fallback (needs 100.7 MB).
        bf16* qb = (bf16*)d_ws;
        bf16* kb = qb + MH;
        bf16* vb = kb + MH;
        dim3 grid(M / BM, HIDDEN / BN), block(256);
        gemm_bt<float, float, bf16><<<grid, block, 0, stream>>>(x, wq, qb, M, HIDDEN, HIDDEN);
        gemm_bt<float, float, bf16><<<grid, block, 0, stream>>>(x, wk, kb, M, HIDDEN, HIDDEN);
        gemm_bt<float, float, bf16><<<grid, block, 0, stream>>>(x, wv, vb, M, HIDDEN, HIDDEN);
        // In-place O->qb safe: each token's stores touch only its own q row.
        attn_heads<<<dim3(M / 16), block, 0, stream>>>(qb, MH, 2 * MH, HIDDEN, qb);
        gemm_bt<bf16, float, float><<<grid, block, 0, stream>>>(qb, wo, out, M, HIDDEN, HIDDEN);
    }
}